// Round 15
// baseline (301.711 us; speedup 1.0000x reference)
//
#include <hip/hip_runtime.h>
#include <cstddef>

// Problem constants (from reference)
#define BB   16
#define HHY  128
#define WWX  256
#define CC   64
#define DDp  12
#define HOUT 1024
#define WOUT 2048

typedef _Float16 hf;                                        // storage type
typedef __fp16 h2 __attribute__((ext_vector_type(2)));      // builtin reg pair

__device__ __forceinline__ h2 u2h(unsigned u) { return __builtin_bit_cast(h2, u); }
__device__ __forceinline__ unsigned pkrtz(float a, float b) {
  return __builtin_bit_cast(unsigned, __builtin_amdgcn_cvt_pkrtz(a, b));
}

#if defined(__has_builtin)
#if __has_builtin(__builtin_amdgcn_fdot2)
#define FDOT2(a, b, c) __builtin_amdgcn_fdot2((a), (b), (c), false)
#endif
#endif
#ifndef FDOT2
#define FDOT2(a, b, c) ((float)(a)[0] * (float)(b)[0] + (float)(a)[1] * (float)(b)[1] + (c))
#endif

// |a-b| dot (1,1) accumulated into c (packed fp16 pairs, f32 accum).
__device__ __forceinline__ float adot(unsigned lu, unsigned ru, float c) {
  const h2 d = u2h(lu) - u2h(ru);
  const unsigned au = __builtin_bit_cast(unsigned, d) & 0x7FFF7FFFu;
  return FDOT2(u2h(au), u2h(0x3C003C00u), c);
}

// ---------------------------------------------------------------------------
// prep: convert conv weights to fp16, repacked [tap27][co][ci] so the ci pairs
// consumed by v_dot2_f32_f16 are contiguous. w1,w2,w3: 432 each; wf: 108.
// ---------------------------------------------------------------------------
__global__ __launch_bounds__(256) void prep_k(const float* __restrict__ w1,
                                              const float* __restrict__ w2,
                                              const float* __restrict__ w3,
                                              const float* __restrict__ wf,
                                              hf* __restrict__ o) {
  const int t = threadIdx.x;
  for (int i = t; i < 432; i += 256) {
    const int t27 = i >> 4;
    const int ci = (i >> 2) & 3;
    const int co = i & 3;
    const int dst = (t27 * 4 + co) * 4 + ci;
    o[dst]       = (hf)w1[i];
    o[432 + dst] = (hf)w2[i];
    o[864 + dst] = (hf)w3[i];
  }
  for (int i = t; i < 108; i += 256) o[1296 + i] = (hf)wf[i];  // [t27][ci], COUT=1
}

// ---------------------------------------------------------------------------
// Kernel 1: cost volume (f32 out) — round-14 version (best of 10 structures;
// bytes-bound at ~2.7 TB/s effective: 268 MB read is irreducible in f32).
// Block = 64-w tile x 12 d; 256 threads = 64 w x 4 dgroups, 3 outputs each.
// fp16 LDS tile (R halo zero-filled), 20 KB, 8 blocks/CU.
// ---------------------------------------------------------------------------
#define CVS 36        // LDS row stride (dwords): 32 data + 4 pad
#define CVHALO 11
#define CVWT 64
#define CVROWS (CVWT + CVHALO + CVWT)  // 75 R rows + 64 L rows = 139

__global__ __launch_bounds__(256, 8) void cost_volume_k(const float* __restrict__ L,
                                                        const float* __restrict__ R,
                                                        float* __restrict__ cost) {
  __shared__ unsigned ls[CVROWS * CVS];   // 139*36*4 = 20016 B
  const int t = threadIdx.x;
  const int wb = blockIdx.x * CVWT;
  const int h = blockIdx.y;
  const int b = blockIdx.z;
  const size_t rowbase = ((size_t)(b * HHY + h)) * WWX;
  const float* Lrow = L + rowbase * CC;
  const float* Rrow = R + rowbase * CC;

  // Stage tile: rows 0..74 = R (global w' = wb-11+row, zero if <0);
  //             rows 75..138 = L (global w = wb+row-75). f32 -> fp16 pairs.
#pragma unroll
  for (int j = 0; j < 9; ++j) {
    const int fi = t + 256 * j;          // float4 id in [0, 2224)
    if (fi < CVROWS * 16) {
      const int row = fi >> 4;
      const int f4 = fi & 15;
      float4 v = make_float4(0.f, 0.f, 0.f, 0.f);
      if (row < CVWT + CVHALO) {
        const int gw = wb - CVHALO + row;
        if (gw >= 0) v = *(const float4*)(Rrow + (size_t)gw * CC + 4 * f4);
      } else {
        const int gw = wb + row - (CVWT + CVHALO);
        v = *(const float4*)(Lrow + (size_t)gw * CC + 4 * f4);
      }
      *(uint2*)(&ls[row * CVS + f4 * 2]) =
          make_uint2(pkrtz(v.x, v.y), pkrtz(v.z, v.w));
    }
  }
  __syncthreads();

  const int w = t & 63;
  const int dg = t >> 6;                 // wave-uniform
  const int rb0 = (w + CVHALO - dg) * CVS;
  const int rb1 = (w + CVHALO - dg - 4) * CVS;
  const int rb2 = (w + CVHALO - dg - 8) * CVS;
  const int rbL = (CVWT + CVHALO + w) * CVS;

  float a0 = 0.f, a1 = 0.f, a2 = 0.f;
#pragma unroll
  for (int k = 0; k < 8; ++k) {
    const uint4 lq = *(const uint4*)(&ls[rbL + 4 * k]);
    const uint4 r0 = *(const uint4*)(&ls[rb0 + 4 * k]);
    a0 = adot(lq.x, r0.x, a0); a0 = adot(lq.y, r0.y, a0);
    a0 = adot(lq.z, r0.z, a0); a0 = adot(lq.w, r0.w, a0);
    const uint4 r1 = *(const uint4*)(&ls[rb1 + 4 * k]);
    a1 = adot(lq.x, r1.x, a1); a1 = adot(lq.y, r1.y, a1);
    a1 = adot(lq.z, r1.z, a1); a1 = adot(lq.w, r1.w, a1);
    const uint4 r2 = *(const uint4*)(&ls[rb2 + 4 * k]);
    a2 = adot(lq.x, r2.x, a2); a2 = adot(lq.y, r2.y, a2);
    a2 = adot(lq.z, r2.z, a2); a2 = adot(lq.w, r2.w, a2);
  }

  // Transpose through LDS for coalesced output stores.
  __syncthreads();                       // tile reads done before overwrite
  float* lo = (float*)ls;
  lo[w * DDp + dg]     = a0;
  lo[w * DDp + dg + 4] = a1;
  lo[w * DDp + dg + 8] = a2;
  __syncthreads();
  if (t < CVWT * DDp / 4) {              // 192 float4
    const float4 v = *(const float4*)(&lo[4 * t]);
    *(float4*)(cost + (rowbase + wb) * DDp + 4 * t) = v;
  }
}

// ---------------------------------------------------------------------------
// conv0: 3x3x3, CIN=1 (f32 cost) -> COUT=4 (fp16 out). Block = one (b,h) row
// (XCD h-remap), thread = w. Row staged f32 in LDS stride 20; weights (108 f)
// wave-uniform global loads; fp16 pack on store. (Round-10 version; at its
// memory floor ~25us -> unchanged.)
// ---------------------------------------------------------------------------
__global__ __launch_bounds__(256) void conv0_k(const float* __restrict__ x,
                                               const float* __restrict__ wt,
                                               const float* __restrict__ bs,
                                               hf* __restrict__ y) {
  constexpr int S = 20;
  __shared__ float ls[WWX * S];   // 20 KB
  const int t = threadIdx.x;
  const int id = blockIdx.x;
  const int h = ((id & 7) << 4) | ((id >> 3) & 15);  // XCD-contiguous h chunks
  const int b = id >> 7;

  float acc[DDp][4];
#pragma unroll
  for (int co = 0; co < 4; ++co) {
    const float bv = bs[co];
#pragma unroll
    for (int d = 0; d < DDp; ++d) acc[d][co] = bv;
  }

#pragma unroll
  for (int kh = 0; kh < 3; ++kh) {
    const int hh = h + kh - 1;
    if (hh < 0 || hh >= HHY) continue;  // block-uniform

    __syncthreads();
    const float* xr = x + ((size_t)(b * HHY + hh) * WWX) * DDp;
#pragma unroll
    for (int j = 0; j < 3; ++j) {
      const int fi4 = t + 256 * j;     // [0,768)
      const int w_ = fi4 / 3;
      const int k_ = fi4 - w_ * 3;
      *(float4*)(&ls[w_ * S + k_ * 4]) = ((const float4*)xr)[fi4];
    }
    __syncthreads();

#pragma unroll
    for (int kw = 0; kw < 3; ++kw) {
      const int ww = t + kw - 1;
      if (ww < 0 || ww >= WWX) continue;
      const float* lp = &ls[ww * S];

      const float* wp = wt + (size_t)(kh * 3 + kw) * 12;
      float wr[12];
#pragma unroll
      for (int i = 0; i < 12; ++i) wr[i] = wp[i];

      float v[DDp];
#pragma unroll
      for (int k = 0; k < 3; ++k)
        ((float4*)v)[k] = *(const float4*)(lp + 4 * k);
#pragma unroll
      for (int vo = 0; vo < DDp; ++vo)
#pragma unroll
        for (int kd = 0; kd < 3; ++kd) {
          const int d = vo + 1 - kd;
          if (d < 0 || d >= DDp) continue;
#pragma unroll
          for (int co = 0; co < 4; ++co)
            acc[d][co] += v[vo] * wr[kd * 4 + co];
        }
    }
  }

  unsigned ov[DDp * 2];
#pragma unroll
  for (int d = 0; d < DDp; ++d) {
    ov[d * 2]     = pkrtz(fmaxf(acc[d][0], 0.f), fmaxf(acc[d][1], 0.f));
    ov[d * 2 + 1] = pkrtz(fmaxf(acc[d][2], 0.f), fmaxf(acc[d][3], 0.f));
  }
  uint4* yp = (uint4*)(y + ((size_t)(b * HHY + h) * WWX + t) * (DDp * 4));
#pragma unroll
  for (int i = 0; i < 6; ++i) yp[i] = ((uint4*)ov)[i];
}

// ---------------------------------------------------------------------------
// Mid/final conv3d 3x3x3, CIN=4, fp16 activations [B,H,W,D,4], f32 accum via
// v_dot2_f32_f16. Block = one (b,h) row (XCD h-remap), thread = w.
// THIS ROUND: kh-row staging via ASYNC DMA (global_load_lds, 16B chunks) —
// no VGPR round-trip, deep load queue (Common-mistake #1; m97 +67%).
// LDS rows padded to 128B (8 chunks, stride 32 uints, 32.8 KB -> 4 blocks/CU);
// SOURCE-swizzled chunks c^(w&7) (rule #21: linear DMA dest + swizzled global
// src), reads apply the same XOR -> 2-way bank phases (free, m136). Dummy
// chunks 6,7 fetch in-bounds garbage (next row's head), never read back.
// Weights fp16 repacked [tap][co][ci], wave-uniform scalar loads.
// FUSE_SM: COUT=1 final conv + softmax(-cost) + disparity regression.
// ---------------------------------------------------------------------------
template <int COUT, bool FUSE_SM>
__global__ __launch_bounds__(256) void convh_k(const hf* __restrict__ x,
                                               const hf* __restrict__ wh,
                                               const float* __restrict__ bs,
                                               void* __restrict__ yv) {
  constexpr int DCH = DDp * 4;        // 48 halves per w (= 24 uints = 6 chunks)
  constexpr int SU  = 32;             // LDS stride per w in uints (8 chunks)
  __shared__ __align__(16) unsigned lsu[WWX * SU];  // 32768 B

  const int t = threadIdx.x;
  const int id = blockIdx.x;
  const int h = ((id & 7) << 4) | ((id >> 3) & 15);
  const int b = id >> 7;

  float acc[DDp][COUT];
#pragma unroll
  for (int co = 0; co < COUT; ++co) {
    const float bv = bs[co];
#pragma unroll
    for (int d = 0; d < DDp; ++d) acc[d][co] = bv;
  }

  const unsigned* whu = (const unsigned*)wh;
  const int wv = t >> 6, ln = t & 63;

#pragma unroll
  for (int kh = 0; kh < 3; ++kh) {
    const int hh = h + kh - 1;
    if (hh < 0 || hh >= HHY) continue;  // block-uniform

    __syncthreads();                    // previous row's readers done
    const unsigned* xr = (const unsigned*)(x + (size_t)(b * HHY + hh) * WWX * DCH);
    // 32 DMA issues per block (8/wave): slot s covers LDS 16B chunk s;
    // row w_ = s>>3, LDS slot sl = s&7 holds global chunk sl^(w_&7).
#pragma unroll
    for (int i = 0; i < 8; ++i) {
      const int s  = (wv * 8 + i) * 64 + ln;   // [0,2048)
      const int w_ = s >> 3;
      const int sl = s & 7;
      const int sc = sl ^ (w_ & 7);            // source chunk (6,7 = dummy)
      __builtin_amdgcn_global_load_lds(xr + (size_t)w_ * 24 + sc * 4,
                                       &lsu[(wv * 8 + i) * 256], 16, 0, 0);
    }
    __syncthreads();                    // drains DMA (vmcnt(0) before barrier)

#pragma unroll
    for (int kw = 0; kw < 3; ++kw) {
      const int ww = t + kw - 1;
      if (ww < 0 || ww >= WWX) continue;  // divergent only at row edges

      // per-tap fp16 weights, wave-uniform scalar loads
      unsigned w01[3][COUT], w23[3][COUT];
      const int tap3 = (kh * 3 + kw) * 3;
#pragma unroll
      for (int kd = 0; kd < 3; ++kd)
#pragma unroll
        for (int co = 0; co < COUT; ++co) {
          const int u0 = ((tap3 + kd) * COUT + co) * 2;
          w01[kd][co] = whu[u0];
          w23[kd][co] = whu[u0 + 1];
        }

      const unsigned* lp = &lsu[ww * SU];
      const int wx = ww & 7;
#pragma unroll
      for (int vo = 0; vo < DDp; ++vo) {
        const int c = (vo >> 1) ^ wx;          // swizzled chunk of this vo
        const uint2 xu = *(const uint2*)(lp + c * 4 + (vo & 1) * 2);
        const h2 x01 = u2h(xu.x), x23 = u2h(xu.y);
#pragma unroll
        for (int kd = 0; kd < 3; ++kd) {
          const int d = vo + 1 - kd;
          if (d < 0 || d >= DDp) continue;
#pragma unroll
          for (int co = 0; co < COUT; ++co)
            acc[d][co] = FDOT2(x01, u2h(w01[kd][co]),
                         FDOT2(x23, u2h(w23[kd][co]), acc[d][co]));
        }
      }
    }
  }

  if constexpr (FUSE_SM) {
    float* y = (float*)yv;
    float mn = acc[0][0];
#pragma unroll
    for (int d = 1; d < DDp; ++d) mn = fminf(mn, acc[d][0]);
    float s = 0.f, sw = 0.f;
#pragma unroll
    for (int d = 0; d < DDp; ++d) {
      const float e = __expf(mn - acc[d][0]);
      s += e;
      sw += e * (float)d;
    }
    y[(size_t)(b * HHY + h) * WWX + t] = sw / s;
  } else {
    hf* y = (hf*)yv;
    unsigned ov[DDp * 2];
#pragma unroll
    for (int d = 0; d < DDp; ++d) {
      ov[d * 2]     = pkrtz(fmaxf(acc[d][0], 0.f), fmaxf(acc[d][1 % COUT], 0.f));
      ov[d * 2 + 1] = pkrtz(fmaxf(acc[d][2 % COUT], 0.f), fmaxf(acc[d][3 % COUT], 0.f));
    }
    uint4* yp = (uint4*)(y + ((size_t)(b * HHY + h) * WWX + t) * DCH);
#pragma unroll
    for (int i = 0; i < 6; ++i) yp[i] = ((uint4*)ov)[i];
  }
}

// ---------------------------------------------------------------------------
// 8x bilinear upsample, 4 outputs per thread (2 input cols x 2 rows -> 4 loads,
// 1 float4 store). jax half-pixel convention; edge renorm == index clamp.
// ---------------------------------------------------------------------------
__global__ __launch_bounds__(256) void resize4_k(const float* __restrict__ pred,
                                                 float* __restrict__ out) {
  const int idx = blockIdx.x * 256 + threadIdx.x;
  const int xg = idx & 511;
  const int y = (idx >> 9) & 1023;
  const int b = idx >> 19;

  const int parity = xg & 1;
  const int m = xg >> 1;
  const int x0 = m - 1 + parity;
  const int x0c = max(x0, 0);
  const int x1c = min(x0 + 1, WWX - 1);
  const float wx0 = (parity ? 0.0625f : 0.5625f);

  const int py = y & 7;
  const int my = y >> 3;
  const int y0 = my - 1 + (py >= 4 ? 1 : 0);
  const float wy = (py >= 4) ? 0.0625f + (py - 4) * 0.125f : 0.5625f + py * 0.125f;
  const int y0c = max(y0, 0);
  const int y1c = min(y0 + 1, HHY - 1);

  const float* pb = pred + (size_t)b * HHY * WWX;
  const float a = pb[y0c * WWX + x0c];
  const float bv = pb[y0c * WWX + x1c];
  const float c = pb[y1c * WWX + x0c];
  const float d = pb[y1c * WWX + x1c];

  const float top0 = a + (bv - a) * wx0;
  const float bot0 = c + (d - c) * wx0;
  const float dtop = (bv - a) * 0.125f;
  const float dbot = (d - c) * 0.125f;

  float4 o;
  o.x = top0 + wy * (bot0 - top0);
  o.y = (top0 + dtop) + wy * ((bot0 + dbot) - (top0 + dtop));
  o.z = (top0 + 2.f * dtop) + wy * ((bot0 + 2.f * dbot) - (top0 + 2.f * dtop));
  o.w = (top0 + 3.f * dtop) + wy * ((bot0 + 3.f * dbot) - (top0 + 3.f * dtop));

  *(float4*)(out + (size_t)idx * 4) = o;
}

// ---------------------------------------------------------------------------
extern "C" void kernel_launch(void* const* d_in, const int* in_sizes, int n_in,
                              void* d_out, int out_size, void* d_ws, size_t ws_size,
                              hipStream_t stream) {
  const float* feat_l = (const float*)d_in[0];
  const float* feat_r = (const float*)d_in[1];
  const float* w0 = (const float*)d_in[2];
  const float* b0 = (const float*)d_in[3];
  const float* w1 = (const float*)d_in[4];
  const float* b1 = (const float*)d_in[5];
  const float* w2 = (const float*)d_in[6];
  const float* b2 = (const float*)d_in[7];
  const float* w3 = (const float*)d_in[8];
  const float* b3 = (const float*)d_in[9];
  const float* wf = (const float*)d_in[10];
  const float* bf = (const float*)d_in[11];
  float* out = (float*)d_out;

  // ws layout: A,B = fp16 activation ping-pong [B,H,W,D,4] (50.3 MB each);
  // C = f32 cost volume (25.2 MB); P = f32 pred (2.1 MB); Wh = fp16 weights.
  char* ws = (char*)d_ws;
  hf*    A  = (hf*)ws;
  hf*    Bf = (hf*)(ws + 50331648);
  float* C  = (float*)(ws + 100663296);
  float* P  = (float*)(ws + 125829120);
  hf*    Wh = (hf*)(ws + 127926272);

  dim3 blk(256);
  prep_k<<<dim3(1), blk, 0, stream>>>(w1, w2, w3, wf, Wh);
  cost_volume_k<<<dim3(WWX / CVWT, HHY, BB), blk, 0, stream>>>(feat_l, feat_r, C);
  conv0_k<<<dim3(HHY * BB), blk, 0, stream>>>(C, w0, b0, A);
  convh_k<4, false><<<dim3(HHY * BB), blk, 0, stream>>>(A,  Wh,        b1, Bf);
  convh_k<4, false><<<dim3(HHY * BB), blk, 0, stream>>>(Bf, Wh + 432,  b2, A);
  convh_k<4, false><<<dim3(HHY * BB), blk, 0, stream>>>(A,  Wh + 864,  b3, Bf);
  convh_k<1, true ><<<dim3(HHY * BB), blk, 0, stream>>>(Bf, Wh + 1296, bf, P);

  const int ngroups = BB * HOUT * (WOUT / 4);
  resize4_k<<<dim3(ngroups / 256), blk, 0, stream>>>(P, out);
}